// Round 6
// baseline (465.359 us; speedup 1.0000x reference)
//
#include <hip/hip_runtime.h>
#include <math.h>

#define NN 10000
#define EE 160000
#define ET 170000
#define FIN 256
#define HH 8
#define HC 512
#define NCLS 40
#define ELLW 96
#define NAGB 2500            // agg blocks (4 nodes each)
#define NCH 79               // 128-row chunks

typedef _Float16 f16;
using f16x8 = __attribute__((ext_vector_type(8))) _Float16;
using f32x4 = __attribute__((ext_vector_type(4))) float;

#define MFMA16(a, b, c) __builtin_amdgcn_mfma_f32_16x16x32_f16((a), (b), (c), 0, 0, 0)

// f32 acc += f16(lo/hi of packed) * f32 w  -- forced mixed-precision FMA
__device__ __forceinline__ void fmamix2(float& alo, float& ahi, unsigned pk, float w) {
    asm("v_fma_mix_f32 %0, %1, %2, %0 op_sel:[0,0,0] op_sel_hi:[1,0,0]"
        : "+v"(alo) : "v"(pk), "v"(w));
    asm("v_fma_mix_f32 %0, %1, %2, %0 op_sel:[1,0,0] op_sel_hi:[1,0,0]"
        : "+v"(ahi) : "v"(pk), "v"(w));
}

// ---------- prep0: cnt zero + chunk-counter zero + W0 transpose ----------
__global__ __launch_bounds__(256) void prep0(const float* __restrict__ W0,
                                             f16* __restrict__ w0T,
                                             int* __restrict__ cnt,
                                             int* __restrict__ cd1,
                                             int* __restrict__ cd2) {
    int i = blockIdx.x * 256 + threadIdx.x;
    if (i < NN) cnt[i] = 0;
    if (i < NCH) { cd1[i] = 0; cd2[i] = 0; }
    if (i < HC * FIN) {
        int n = i >> 8, k = i & 255;
        w0T[i] = (f16)W0[(size_t)k * HC + n];
    }
}

// ---------- mega0: gemmL0 (fp32 A) + scatter + W1/W2 transpose ----------
__global__ __launch_bounds__(512) void mega0(const float* __restrict__ x,
                                             const f16* __restrict__ w0T,
                                             const float* __restrict__ a_src,
                                             const float* __restrict__ a_dst,
                                             const int* __restrict__ ei,
                                             const float* __restrict__ W1,
                                             const float* __restrict__ W2,
                                             f16* __restrict__ hx2,
                                             float* __restrict__ al_s,
                                             float* __restrict__ al_d,
                                             int* __restrict__ cnt,
                                             int* __restrict__ ell,
                                             f16* __restrict__ w1T,
                                             f16* __restrict__ w2T) {
    __shared__ f16 Bs[64 * FIN];          // 32 KB
    int b = blockIdx.x;
    int t = threadIdx.x;
    if (b >= 316) {
        if (b < 649) {                    // scatter
            int e = (b - 316) * 512 + t;
            if (e < ET) {
                int s, d;
                if (e < EE) { s = ei[e]; d = ei[EE + e]; }
                else        { s = e - EE; d = s; }
                int pos = atomicAdd(&cnt[d], 1);
                if (pos < ELLW) ell[(size_t)d * ELLW + pos] = s;
            }
        } else if (b < 1161) {            // W1 transpose
            int j = (b - 649) * 512 + t;
            int n = j >> 9, k = j & 511;
            w1T[j] = (f16)W1[(size_t)k * HC + n];
        } else {                          // W2 transpose
            int j = (b - 1161) * 512 + t;
            if (j < NCLS * HC) {
                int n = j >> 9, k = j & 511;
                w2T[j] = (f16)W2[(size_t)k * NCLS + n];
            }
        }
        return;
    }
    // ---- gemm L0: fp32 A rows -> f16 frags, B-resident LDS ----
    int hp = b & 3, chunk = b >> 2;
    int lane = t & 63, w = t >> 6;
    int fm = lane & 15, g = lane >> 4;
    int bm = chunk * 128 + w * 16;
    int row = bm + fm;
    bool rok = row < NN;

    f16x8 af[8];
#pragma unroll
    for (int kk = 0; kk < 8; ++kk) {
        float4 lo = make_float4(0.f, 0.f, 0.f, 0.f), hi = lo;
        if (rok) {
            const float* ap = x + (size_t)row * FIN + kk * 32 + g * 8;
            lo = *(const float4*)ap;
            hi = *(const float4*)(ap + 4);
        }
        f16x8 v;
        v[0] = (f16)lo.x; v[1] = (f16)lo.y; v[2] = (f16)lo.z; v[3] = (f16)lo.w;
        v[4] = (f16)hi.x; v[5] = (f16)hi.y; v[6] = (f16)hi.z; v[7] = (f16)hi.w;
        af[kk] = v;
    }

    for (int sl = 0; sl < 2; ++sl) {
        int h = hp * 2 + sl;
        const f16* bsrc = w0T + (size_t)h * 64 * FIN;
        for (int c = t; c < 64 * 32; c += 512) {
            int brow = c >> 5, j = c & 31;
            uint4 v = *(const uint4*)(bsrc + (size_t)brow * FIN + j * 8);
            *(uint4*)&Bs[(size_t)brow * FIN + ((j ^ (brow & 7)) * 8)] = v;
        }
        __syncthreads();

        f32x4 acc[4] = {};
#pragma unroll
        for (int kk = 0; kk < 8; ++kk) {
#pragma unroll
            for (int nt = 0; nt < 4; ++nt) {
                f16x8 bb = *(const f16x8*)
                    &Bs[(nt * 16 + fm) * FIN + (((kk * 4 + g) ^ (fm & 7)) * 8)];
                acc[nt] = MFMA16(af[kk], bb, acc[nt]);
            }
        }

        float asc[4], adc[4];
#pragma unroll
        for (int nt = 0; nt < 4; ++nt) {
            asc[nt] = a_src[h * 64 + nt * 16 + fm];
            adc[nt] = a_dst[h * 64 + nt * 16 + fm];
        }
#pragma unroll
        for (int r = 0; r < 4; ++r) {
            int orow = bm + g * 4 + r;          // C/D: row=(lane>>4)*4+reg
            float s = acc[0][r] * asc[0] + acc[1][r] * asc[1] +
                      acc[2][r] * asc[2] + acc[3][r] * asc[3];
            float d = acc[0][r] * adc[0] + acc[1][r] * adc[1] +
                      acc[2][r] * adc[2] + acc[3][r] * adc[3];
#pragma unroll
            for (int off = 1; off < 16; off <<= 1) {
                s += __shfl_xor(s, off);
                d += __shfl_xor(d, off);
            }
            if (orow < NN) {
                if (fm == 0) {
                    al_s[orow * 8 + h] = s;
                    al_d[orow * 8 + h] = d;
                }
#pragma unroll
                for (int nt = 0; nt < 4; ++nt)
                    hx2[(size_t)orow * HC + h * 64 + nt * 16 + fm] =
                        (f16)acc[nt][r];
            }
        }
        __syncthreads();
    }
}

// ---------- shared agg body: 4 nodes per 512-thr block, 2 waves/node ----------
struct SM {
    union {
        f16 Bs[64 * 256];                              // 32 KB GEMM stage
        struct { float ab[4][64][8]; float db[4][64]; } a;  // 33 KB agg combine
    } u;
};

__device__ __forceinline__ void agg_body(SM& sm,
                                         const f16* __restrict__ hx2,
                                         const float* __restrict__ al_s,
                                         const float* __restrict__ al_d,
                                         const int* __restrict__ cnt,
                                         const int* __restrict__ ell,
                                         const float* __restrict__ bias,
                                         f16* __restrict__ outF, int b) {
    int t = threadIdx.x;
    int lane = t & 63, w = t >> 6;
    int p = w >> 1, sub = w & 1;
    int n = b * 4 + p;
    int ch = lane * 8;
    int h = lane >> 3;
    float acc[8] = {0.f, 0.f, 0.f, 0.f, 0.f, 0.f, 0.f, 0.f};
    float den = 0.f;
    float ald = al_d[n * HH + h];
    int dg = cnt[n]; if (dg > ELLW) dg = ELLW;
    const int* ep = ell + (size_t)n * ELLW;
    int nq = dg >> 2;
    for (int q = sub; q < nq; q += 2) {
        int4 ss = *(const int4*)(ep + (q << 2));
        float e0 = al_s[ss.x * HH + h], e1 = al_s[ss.y * HH + h];
        float e2 = al_s[ss.z * HH + h], e3 = al_s[ss.w * HH + h];
        uint4 v0 = *(const uint4*)(hx2 + (size_t)ss.x * HC + ch);
        uint4 v1 = *(const uint4*)(hx2 + (size_t)ss.y * HC + ch);
        uint4 v2 = *(const uint4*)(hx2 + (size_t)ss.z * HC + ch);
        uint4 v3 = *(const uint4*)(hx2 + (size_t)ss.w * HC + ch);
        e0 += ald; e0 = e0 > 0.f ? e0 : 0.2f * e0;
        e1 += ald; e1 = e1 > 0.f ? e1 : 0.2f * e1;
        e2 += ald; e2 = e2 > 0.f ? e2 : 0.2f * e2;
        e3 += ald; e3 = e3 > 0.f ? e3 : 0.2f * e3;
        float w0 = __expf(e0), w1 = __expf(e1);
        float w2 = __expf(e2), w3 = __expf(e3);
        unsigned q0[4] = {v0.x, v0.y, v0.z, v0.w};
        unsigned q1[4] = {v1.x, v1.y, v1.z, v1.w};
        unsigned q2[4] = {v2.x, v2.y, v2.z, v2.w};
        unsigned q3[4] = {v3.x, v3.y, v3.z, v3.w};
#pragma unroll
        for (int j = 0; j < 4; ++j) {
            fmamix2(acc[2 * j], acc[2 * j + 1], q0[j], w0);
            fmamix2(acc[2 * j], acc[2 * j + 1], q1[j], w1);
            fmamix2(acc[2 * j], acc[2 * j + 1], q2[j], w2);
            fmamix2(acc[2 * j], acc[2 * j + 1], q3[j], w3);
        }
        den += w0 + w1 + w2 + w3;
    }
    if (sub == (nq & 1)) {                  // tail to lighter wave
        for (int i2 = nq << 2; i2 < dg; ++i2) {
            int s = ep[i2];
            float e = al_s[s * HH + h] + ald;
            e = e > 0.f ? e : 0.2f * e;
            float wgt = __expf(e);
            uint4 v = *(const uint4*)(hx2 + (size_t)s * HC + ch);
            unsigned qq[4] = {v.x, v.y, v.z, v.w};
#pragma unroll
            for (int j = 0; j < 4; ++j)
                fmamix2(acc[2 * j], acc[2 * j + 1], qq[j], wgt);
            den += wgt;
        }
    }
    if (sub == 1) {
#pragma unroll
        for (int j = 0; j < 8; ++j) sm.u.a.ab[p][lane][j] = acc[j];
        sm.u.a.db[p][lane] = den;
    }
    __syncthreads();
    if (sub == 0) {
#pragma unroll
        for (int j = 0; j < 8; ++j) acc[j] += sm.u.a.ab[p][lane][j];
        den += sm.u.a.db[p][lane];
        float inv = 1.f / (den + 1e-16f);
        float4 b0v = *(const float4*)(bias + ch);
        float4 b1v = *(const float4*)(bias + ch + 4);
        float bb[8] = {b0v.x, b0v.y, b0v.z, b0v.w, b1v.x, b1v.y, b1v.z, b1v.w};
        f16x8 o;
#pragma unroll
        for (int j = 0; j < 8; ++j) {
            float v = acc[j] * inv + bb[j];
            v = v > 0.f ? v : expm1f(v);        // ELU
            o[j] = (f16)v;
        }
        *(uint4*)(outF + (size_t)n * HC + ch) = __builtin_bit_cast(uint4, o);
    }
    __syncthreads();                            // drain stores before publish
}

// ---------- fused1: agg layer0 (producer) + gemm layer1 (consumer) ----------
__global__ __launch_bounds__(512, 4) void fused1(const f16* __restrict__ hxA,
                                                 const float* __restrict__ als0,
                                                 const float* __restrict__ ald0,
                                                 const int* __restrict__ cnt,
                                                 const int* __restrict__ ell,
                                                 const float* __restrict__ b0,
                                                 f16* __restrict__ fA,
                                                 const f16* __restrict__ w1T,
                                                 const float* __restrict__ as1,
                                                 const float* __restrict__ ad1,
                                                 f16* __restrict__ hxB,
                                                 float* __restrict__ als1,
                                                 float* __restrict__ ald1,
                                                 int* __restrict__ cd) {
    __shared__ SM sm;
    int b = blockIdx.x;
    int t = threadIdx.x;
    if (b < NAGB) {
        agg_body(sm, hxA, als0, ald0, cnt, ell, b0, fA, b);
        if (t == 0) {
            __threadfence();                       // wb L2 -> coherent point
            atomicAdd(&cd[b >> 5], 1);             // publish chunk progress
        }
        return;
    }
    // ---- gemm1 consumer: chunk of 128 rows, 4 head-pairs ----
    int c = b - NAGB;
    int hp = c & 3, chunk = c >> 2;
    int target = NAGB - 32 * chunk; if (target > 32) target = 32;
    if (t == 0) {
        while (__hip_atomic_load(&cd[chunk], __ATOMIC_RELAXED,
                                 __HIP_MEMORY_SCOPE_AGENT) < target)
            __builtin_amdgcn_s_sleep(8);
    }
    __syncthreads();
    __threadfence();                               // acquire: invalidate stale
    int lane = t & 63, w = t >> 6;
    int fm = lane & 15, g = lane >> 4;
    int bm = chunk * 128 + w * 16;
    int row = bm + fm;
    bool rok = row < NN;

    f32x4 acc[2][4] = {};
    for (int kh = 0; kh < 2; ++kh) {
        f16x8 af[8];
#pragma unroll
        for (int kk = 0; kk < 8; ++kk) {
            uint4 r = rok ? *(const uint4*)(fA + (size_t)row * HC + kh * 256 +
                                            kk * 32 + g * 8)
                          : make_uint4(0u, 0u, 0u, 0u);
            af[kk] = __builtin_bit_cast(f16x8, r);
        }
        for (int sl = 0; sl < 2; ++sl) {
            int h2 = hp * 2 + sl;
            const f16* bsrc = w1T + (size_t)h2 * 64 * HC + kh * 256;
            __syncthreads();                       // prior readers done
            for (int cc = t; cc < 64 * 32; cc += 512) {
                int brow = cc >> 5, j = cc & 31;
                uint4 v = *(const uint4*)(bsrc + (size_t)brow * HC + j * 8);
                *(uint4*)&sm.u.Bs[brow * 256 + ((j ^ (brow & 7)) * 8)] = v;
            }
            __syncthreads();
#pragma unroll
            for (int kk = 0; kk < 8; ++kk) {
#pragma unroll
                for (int nt = 0; nt < 4; ++nt) {
                    f16x8 bb = *(const f16x8*)
                        &sm.u.Bs[(nt * 16 + fm) * 256 + (((kk * 4 + g) ^ (fm & 7)) * 8)];
                    acc[sl][nt] = MFMA16(af[kk], bb, acc[sl][nt]);
                }
            }
        }
    }
#pragma unroll
    for (int sl = 0; sl < 2; ++sl) {
        int h2 = hp * 2 + sl;
        float asc[4], adc[4];
#pragma unroll
        for (int nt = 0; nt < 4; ++nt) {
            asc[nt] = as1[h2 * 64 + nt * 16 + fm];
            adc[nt] = ad1[h2 * 64 + nt * 16 + fm];
        }
#pragma unroll
        for (int r = 0; r < 4; ++r) {
            int orow = bm + g * 4 + r;
            float s = acc[sl][0][r] * asc[0] + acc[sl][1][r] * asc[1] +
                      acc[sl][2][r] * asc[2] + acc[sl][3][r] * asc[3];
            float d = acc[sl][0][r] * adc[0] + acc[sl][1][r] * adc[1] +
                      acc[sl][2][r] * adc[2] + acc[sl][3][r] * adc[3];
#pragma unroll
            for (int off = 1; off < 16; off <<= 1) {
                s += __shfl_xor(s, off);
                d += __shfl_xor(d, off);
            }
            if (orow < NN) {
                if (fm == 0) {
                    als1[orow * 8 + h2] = s;
                    ald1[orow * 8 + h2] = d;
                }
#pragma unroll
                for (int nt = 0; nt < 4; ++nt)
                    hxB[(size_t)orow * HC + h2 * 64 + nt * 16 + fm] =
                        (f16)acc[sl][nt][r];
            }
        }
    }
}

// ---------- fused2: agg layer1 (producer) + gemm layer2 (consumer) ----------
__global__ __launch_bounds__(512, 4) void fused2(const f16* __restrict__ hxB,
                                                 const float* __restrict__ als1,
                                                 const float* __restrict__ ald1,
                                                 const int* __restrict__ cnt,
                                                 const int* __restrict__ ell,
                                                 const float* __restrict__ b1,
                                                 f16* __restrict__ fB,
                                                 const f16* __restrict__ w2T,
                                                 const float* __restrict__ as2,
                                                 const float* __restrict__ ad2,
                                                 float* __restrict__ hx40,
                                                 float* __restrict__ als2,
                                                 float* __restrict__ ald2,
                                                 int* __restrict__ cd) {
    __shared__ SM sm;
    int b = blockIdx.x;
    int t = threadIdx.x;
    if (b < NAGB) {
        agg_body(sm, hxB, als1, ald1, cnt, ell, b1, fB, b);
        if (t == 0) {
            __threadfence();
            atomicAdd(&cd[b >> 5], 1);
        }
        return;
    }
    // ---- gemm2 consumer: chunk of 128 rows, 512 -> 40 ----
    int chunk = b - NAGB;                          // 0..78
    int target = NAGB - 32 * chunk; if (target > 32) target = 32;
    if (t == 0) {
        while (__hip_atomic_load(&cd[chunk], __ATOMIC_RELAXED,
                                 __HIP_MEMORY_SCOPE_AGENT) < target)
            __builtin_amdgcn_s_sleep(8);
    }
    __syncthreads();
    __threadfence();
    int lane = t & 63, w = t >> 6;
    int fm = lane & 15, g = lane >> 4;
    int bm = chunk * 128 + w * 16;
    int row = bm + fm;
    bool rok = row < NN;

    f32x4 acc[3] = {};
    for (int kh = 0; kh < 2; ++kh) {
        f16x8 af[8];
#pragma unroll
        for (int kk = 0; kk < 8; ++kk) {
            uint4 r = rok ? *(const uint4*)(fB + (size_t)row * HC + kh * 256 +
                                            kk * 32 + g * 8)
                          : make_uint4(0u, 0u, 0u, 0u);
            af[kk] = __builtin_bit_cast(f16x8, r);
        }
        __syncthreads();
        for (int cc = t; cc < 48 * 32; cc += 512) {
            int brow = cc >> 5, j = cc & 31;
            uint4 v = make_uint4(0u, 0u, 0u, 0u);
            if (brow < NCLS)
                v = *(const uint4*)(w2T + (size_t)brow * HC + kh * 256 + j * 8);
            *(uint4*)&sm.u.Bs[brow * 256 + ((j ^ (brow & 7)) * 8)] = v;
        }
        __syncthreads();
#pragma unroll
        for (int kk = 0; kk < 8; ++kk) {
#pragma unroll
            for (int nt = 0; nt < 3; ++nt) {
                f16x8 bb = *(const f16x8*)
                    &sm.u.Bs[(nt * 16 + fm) * 256 + (((kk * 4 + g) ^ (fm & 7)) * 8)];
                acc[nt] = MFMA16(af[kk], bb, acc[nt]);
            }
        }
    }
    float a2s[3], a2d[3];
#pragma unroll
    for (int nt = 0; nt < 3; ++nt) {
        int col = nt * 16 + fm;
        a2s[nt] = (col < NCLS) ? as2[col] : 0.f;
        a2d[nt] = (col < NCLS) ? ad2[col] : 0.f;
    }
#pragma unroll
    for (int r = 0; r < 4; ++r) {
        int orow = bm + g * 4 + r;
        float s = acc[0][r] * a2s[0] + acc[1][r] * a2s[1] + acc[2][r] * a2s[2];
        float d = acc[0][r] * a2d[0] + acc[1][r] * a2d[1] + acc[2][r] * a2d[2];
#pragma unroll
        for (int off = 1; off < 16; off <<= 1) {
            s += __shfl_xor(s, off);
            d += __shfl_xor(d, off);
        }
        if (orow < NN) {
            if (fm == 0) { als2[orow] = s; ald2[orow] = d; }
#pragma unroll
            for (int nt = 0; nt < 3; ++nt) {
                int col = nt * 16 + fm;
                if (col < NCLS) hx40[(size_t)orow * NCLS + col] = acc[nt][r];
            }
        }
    }
}

// ---------- final aggregate (H=1, C=40), 4 waves/block ----------
__global__ __launch_bounds__(256) void agg2_final(const float* __restrict__ hx40,
                                                  const float* __restrict__ als,
                                                  const float* __restrict__ aldp,
                                                  const int* __restrict__ cnt,
                                                  const int* __restrict__ ell,
                                                  const float* __restrict__ b2,
                                                  float* __restrict__ out) {
    int t = threadIdx.x;
    int n = blockIdx.x * 4 + (t >> 6);
    int c = t & 63;
    if (n >= NN) return;
    float ald = aldp[n];
    int dg = cnt[n]; if (dg > ELLW) dg = ELLW;
    const int* ep = ell + (size_t)n * ELLW;
    float acc = 0.f, den = 0.f;
    int i = 0;
    for (; i + 4 <= dg; i += 4) {
        int4 ss = *(const int4*)(ep + i);
        float e0 = als[ss.x], e1 = als[ss.y], e2 = als[ss.z], e3 = als[ss.w];
        float v0 = 0.f, v1 = 0.f, v2 = 0.f, v3 = 0.f;
        if (c < NCLS) {
            v0 = hx40[(size_t)ss.x * NCLS + c];
            v1 = hx40[(size_t)ss.y * NCLS + c];
            v2 = hx40[(size_t)ss.z * NCLS + c];
            v3 = hx40[(size_t)ss.w * NCLS + c];
        }
        e0 += ald; e0 = e0 > 0.f ? e0 : 0.2f * e0;
        e1 += ald; e1 = e1 > 0.f ? e1 : 0.2f * e1;
        e2 += ald; e2 = e2 > 0.f ? e2 : 0.2f * e2;
        e3 += ald; e3 = e3 > 0.f ? e3 : 0.2f * e3;
        float w0 = __expf(e0), w1 = __expf(e1), w2 = __expf(e2), w3 = __expf(e3);
        acc += w0 * v0 + w1 * v1 + w2 * v2 + w3 * v3;
        den += w0 + w1 + w2 + w3;
    }
    for (; i < dg; ++i) {
        int s = ep[i];
        float e = als[s] + ald;
        e = e > 0.f ? e : 0.2f * e;
        float wgt = __expf(e);
        if (c < NCLS) acc += wgt * hx40[(size_t)s * NCLS + c];
        den += wgt;
    }
    if (c < NCLS) out[(size_t)n * NCLS + c] = acc / (den + 1e-16f) + b2[c];
}

extern "C" void kernel_launch(void* const* d_in, const int* in_sizes, int n_in,
                              void* d_out, int out_size, void* d_ws, size_t ws_size,
                              hipStream_t stream) {
    const float* x   = (const float*)d_in[0];
    const int*   ei  = (const int*)  d_in[1];
    const float* W0  = (const float*)d_in[2];
    const float* as0 = (const float*)d_in[3];
    const float* ad0 = (const float*)d_in[4];
    const float* b0  = (const float*)d_in[5];
    const float* W1  = (const float*)d_in[6];
    const float* as1 = (const float*)d_in[7];
    const float* ad1 = (const float*)d_in[8];
    const float* b1  = (const float*)d_in[9];
    const float* W2  = (const float*)d_in[10];
    const float* as2 = (const float*)d_in[11];
    const float* ad2 = (const float*)d_in[12];
    const float* b2  = (const float*)d_in[13];
    float* out = (float*)d_out;

    char* p = (char*)d_ws;
    int* cnt  = (int*)p; p += 40064;
    int* cd1  = (int*)p; p += 512;
    int* cd2  = (int*)p; p += 512;
    int* ell  = (int*)p; p += (size_t)NN * ELLW * 4;    // 3.84 MB
    f16* w0T  = (f16*)p; p += HC * FIN * 2;
    f16* w1T  = (f16*)p; p += HC * HC * 2;
    f16* w2T  = (f16*)p; p += NCLS * HC * 2;
    f16* hxA  = (f16*)p; p += (size_t)NN * HC * 2;
    f16* hxB  = (f16*)p; p += (size_t)NN * HC * 2;
    f16* fA   = (f16*)p; p += (size_t)NN * HC * 2;
    f16* fB   = (f16*)p; p += (size_t)NN * HC * 2;
    float* hx40 = (float*)p; p += (size_t)NN * NCLS * 4;
    float* als0 = (float*)p; p += NN * HH * 4;
    float* ald0 = (float*)p; p += NN * HH * 4;
    float* als1 = (float*)p; p += NN * HH * 4;
    float* ald1 = (float*)p; p += NN * HH * 4;
    float* als2 = (float*)p; p += NN * 4;
    float* ald2 = (float*)p; p += NN * 4;

    // 1) prep: cnt/chunk-counter zero + W0 transpose
    prep0<<<(HC * FIN + 255) / 256, 256, 0, stream>>>(W0, w0T, cnt, cd1, cd2);
    // 2) mega0: gemm L0 (316) + scatter (333) + W1 (512) + W2 (40) = 1201 blocks
    mega0<<<1201, 512, 0, stream>>>(x, w0T, as0, ad0, ei, W1, W2,
                                    hxA, als0, ald0, cnt, ell, w1T, w2T);
    // 3) fused: agg L0 (2500 producers) + gemm L1 (316 consumers)
    fused1<<<NAGB + 316, 512, 0, stream>>>(hxA, als0, ald0, cnt, ell, b0, fA,
                                           w1T, as1, ad1, hxB, als1, ald1, cd1);
    // 4) fused: agg L1 (2500 producers) + gemm L2 (79 consumers)
    fused2<<<NAGB + NCH, 512, 0, stream>>>(hxB, als1, ald1, cnt, ell, b1, fB,
                                           w2T, as2, ad2, hx40, als2, ald2, cd2);
    // 5) final aggregate
    agg2_final<<<(NN + 3) / 4, 256, 0, stream>>>(hx40, als2, ald2, cnt, ell, b2, out);
}

// Round 7
// 211.704 us; speedup vs baseline: 2.1982x; 2.1982x over previous
//
#include <hip/hip_runtime.h>
#include <math.h>

#define NN 10000
#define EE 160000
#define ET 170000
#define FIN 256
#define HH 8
#define HC 512
#define NCLS 40
#define ELLW 96

typedef _Float16 f16;
using f16x8 = __attribute__((ext_vector_type(8))) _Float16;
using f32x4 = __attribute__((ext_vector_type(4))) float;
using u32x4 = __attribute__((ext_vector_type(4))) unsigned int;

#define MFMA16(a, b, c) __builtin_amdgcn_mfma_f32_16x16x32_f16((a), (b), (c), 0, 0, 0)

// ---- non-temporal stores: bypass writer-XCD L2 so consumer XCDs get clean
// L3 hits instead of the cross-XCD dirty-line probe path ----
__device__ __forceinline__ void nt_u4(void* p, uint4 v) {
    __builtin_nontemporal_store(__builtin_bit_cast(u32x4, v), (u32x4*)p);
}
__device__ __forceinline__ void nt_f(float* p, float v) {
    __builtin_nontemporal_store(v, p);
}
__device__ __forceinline__ void nt_h(f16* p, f16 v) {
    __builtin_nontemporal_store(v, p);
}
__device__ __forceinline__ void nt_i(int* p, int v) {
    __builtin_nontemporal_store(v, p);
}

// f32 acc += f16(lo/hi of packed) * f32 w  -- forced mixed-precision FMA
__device__ __forceinline__ void fmamix2(float& alo, float& ahi, unsigned pk, float w) {
    asm("v_fma_mix_f32 %0, %1, %2, %0 op_sel:[0,0,0] op_sel_hi:[1,0,0]"
        : "+v"(alo) : "v"(pk), "v"(w));
    asm("v_fma_mix_f32 %0, %1, %2, %0 op_sel:[1,0,0] op_sel_hi:[1,0,0]"
        : "+v"(ahi) : "v"(pk), "v"(w));
}

// ---------- prep0: cnt zero + W0 transpose (tiny) ----------
__global__ __launch_bounds__(256) void prep0(const float* __restrict__ W0,
                                             f16* __restrict__ w0T,
                                             int* __restrict__ cnt) {
    int i = blockIdx.x * 256 + threadIdx.x;
    if (i < NN) cnt[i] = 0;
    if (i < HC * FIN) {
        int n = i >> 8, k = i & 255;
        nt_h(&w0T[i], (f16)W0[(size_t)k * HC + n]);
    }
}

// ---------- mega0: gemmL0 (fp32 A) + scatter + W1/W2 transpose ----------
__global__ __launch_bounds__(512) void mega0(const float* __restrict__ x,
                                             const f16* __restrict__ w0T,
                                             const float* __restrict__ a_src,
                                             const float* __restrict__ a_dst,
                                             const int* __restrict__ ei,
                                             const float* __restrict__ W1,
                                             const float* __restrict__ W2,
                                             f16* __restrict__ hx2,
                                             float* __restrict__ al_s,
                                             float* __restrict__ al_d,
                                             int* __restrict__ cnt,
                                             int* __restrict__ ell,
                                             f16* __restrict__ w1T,
                                             f16* __restrict__ w2T) {
    __shared__ f16 Bs[64 * FIN];          // 32 KB
    int b = blockIdx.x;
    int t = threadIdx.x;
    if (b >= 316) {
        if (b < 649) {                    // scatter
            int e = (b - 316) * 512 + t;
            if (e < ET) {
                int s, d;
                if (e < EE) { s = ei[e]; d = ei[EE + e]; }
                else        { s = e - EE; d = s; }
                int pos = atomicAdd(&cnt[d], 1);
                if (pos < ELLW) nt_i(&ell[(size_t)d * ELLW + pos], s);
            }
        } else if (b < 1161) {            // W1 transpose
            int j = (b - 649) * 512 + t;
            int n = j >> 9, k = j & 511;
            nt_h(&w1T[j], (f16)W1[(size_t)k * HC + n]);
        } else {                          // W2 transpose
            int j = (b - 1161) * 512 + t;
            if (j < NCLS * HC) {
                int n = j >> 9, k = j & 511;
                nt_h(&w2T[j], (f16)W2[(size_t)k * NCLS + n]);
            }
        }
        return;
    }
    // ---- gemm L0: fp32 A rows -> f16 frags, B-resident LDS ----
    int hp = b & 3, chunk = b >> 2;
    int lane = t & 63, w = t >> 6;
    int fm = lane & 15, g = lane >> 4;
    int bm = chunk * 128 + w * 16;
    int row = bm + fm;
    bool rok = row < NN;

    f16x8 af[8];
#pragma unroll
    for (int kk = 0; kk < 8; ++kk) {
        float4 lo = make_float4(0.f, 0.f, 0.f, 0.f), hi = lo;
        if (rok) {
            const float* ap = x + (size_t)row * FIN + kk * 32 + g * 8;
            lo = *(const float4*)ap;
            hi = *(const float4*)(ap + 4);
        }
        f16x8 v;
        v[0] = (f16)lo.x; v[1] = (f16)lo.y; v[2] = (f16)lo.z; v[3] = (f16)lo.w;
        v[4] = (f16)hi.x; v[5] = (f16)hi.y; v[6] = (f16)hi.z; v[7] = (f16)hi.w;
        af[kk] = v;
    }

    for (int sl = 0; sl < 2; ++sl) {
        int h = hp * 2 + sl;
        const f16* bsrc = w0T + (size_t)h * 64 * FIN;
        for (int c = t; c < 64 * 32; c += 512) {
            int brow = c >> 5, j = c & 31;
            uint4 v = *(const uint4*)(bsrc + (size_t)brow * FIN + j * 8);
            *(uint4*)&Bs[(size_t)brow * FIN + ((j ^ (brow & 7)) * 8)] = v;
        }
        __syncthreads();

        f32x4 acc[4] = {};
#pragma unroll
        for (int kk = 0; kk < 8; ++kk) {
#pragma unroll
            for (int nt = 0; nt < 4; ++nt) {
                f16x8 bb = *(const f16x8*)
                    &Bs[(nt * 16 + fm) * FIN + (((kk * 4 + g) ^ (fm & 7)) * 8)];
                acc[nt] = MFMA16(af[kk], bb, acc[nt]);
            }
        }

        float asc[4], adc[4];
#pragma unroll
        for (int nt = 0; nt < 4; ++nt) {
            asc[nt] = a_src[h * 64 + nt * 16 + fm];
            adc[nt] = a_dst[h * 64 + nt * 16 + fm];
        }
#pragma unroll
        for (int r = 0; r < 4; ++r) {
            int orow = bm + g * 4 + r;          // C/D: row=(lane>>4)*4+reg
            float s = acc[0][r] * asc[0] + acc[1][r] * asc[1] +
                      acc[2][r] * asc[2] + acc[3][r] * asc[3];
            float d = acc[0][r] * adc[0] + acc[1][r] * adc[1] +
                      acc[2][r] * adc[2] + acc[3][r] * adc[3];
#pragma unroll
            for (int off = 1; off < 16; off <<= 1) {
                s += __shfl_xor(s, off);
                d += __shfl_xor(d, off);
            }
            if (orow < NN) {
                if (fm == 0) {
                    nt_f(&al_s[orow * 8 + h], s);
                    nt_f(&al_d[orow * 8 + h], d);
                }
#pragma unroll
                for (int nt = 0; nt < 4; ++nt)
                    nt_h(&hx2[(size_t)orow * HC + h * 64 + nt * 16 + fm],
                         (f16)acc[nt][r]);
            }
        }
        __syncthreads();
    }
}

// ---------- GEMM + fused attn (f16 A), layer 1 ----------
template <int K>
__global__ __launch_bounds__(512) void gemm_attn(const f16* __restrict__ A,
                                                 const f16* __restrict__ BT,
                                                 const float* __restrict__ a_src,
                                                 const float* __restrict__ a_dst,
                                                 f16* __restrict__ hx2,
                                                 float* __restrict__ al_s,
                                                 float* __restrict__ al_d) {
    constexpr int KK = K / 32;
    constexpr int CH = K / 8;
    __shared__ f16 Bs[64 * K];
    int t = threadIdx.x;
    int hp = blockIdx.x;
    int lane = t & 63, w = t >> 6;
    int fm = lane & 15, g = lane >> 4;
    int bm = blockIdx.y * 128 + w * 16;
    int row = bm + fm;
    bool rok = row < NN;

    f16x8 af[KK];
#pragma unroll
    for (int kk = 0; kk < KK; ++kk) {
        uint4 r = rok ? *(const uint4*)(A + (size_t)row * K + kk * 32 + g * 8)
                      : make_uint4(0u, 0u, 0u, 0u);
        af[kk] = __builtin_bit_cast(f16x8, r);
    }

    for (int sl = 0; sl < 2; ++sl) {
        int h = hp * 2 + sl;
        const f16* bsrc = BT + (size_t)h * 64 * K;
        for (int c = t; c < 64 * CH; c += 512) {
            int brow = c / CH;
            int j = c - brow * CH;
            uint4 v = *(const uint4*)(bsrc + (size_t)brow * K + j * 8);
            *(uint4*)&Bs[(size_t)brow * K + ((j ^ (brow & 7)) * 8)] = v;
        }
        __syncthreads();

        f32x4 acc[4] = {};
#pragma unroll
        for (int kk = 0; kk < KK; ++kk) {
#pragma unroll
            for (int nt = 0; nt < 4; ++nt) {
                f16x8 b = *(const f16x8*)
                    &Bs[(nt * 16 + fm) * K + (((kk * 4 + g) ^ (fm & 7)) * 8)];
                acc[nt] = MFMA16(af[kk], b, acc[nt]);
            }
        }

        float asc[4], adc[4];
#pragma unroll
        for (int nt = 0; nt < 4; ++nt) {
            asc[nt] = a_src[h * 64 + nt * 16 + fm];
            adc[nt] = a_dst[h * 64 + nt * 16 + fm];
        }
#pragma unroll
        for (int r = 0; r < 4; ++r) {
            int orow = bm + g * 4 + r;
            float s = acc[0][r] * asc[0] + acc[1][r] * asc[1] +
                      acc[2][r] * asc[2] + acc[3][r] * asc[3];
            float d = acc[0][r] * adc[0] + acc[1][r] * adc[1] +
                      acc[2][r] * adc[2] + acc[3][r] * adc[3];
#pragma unroll
            for (int off = 1; off < 16; off <<= 1) {
                s += __shfl_xor(s, off);
                d += __shfl_xor(d, off);
            }
            if (orow < NN) {
                if (fm == 0) {
                    nt_f(&al_s[orow * 8 + h], s);
                    nt_f(&al_d[orow * 8 + h], d);
                }
#pragma unroll
                for (int nt = 0; nt < 4; ++nt)
                    nt_h(&hx2[(size_t)orow * HC + h * 64 + nt * 16 + fm],
                         (f16)acc[nt][r]);
            }
        }
        __syncthreads();
    }
}

// ---------- layer 2: barrier-free B-resident GEMM 512->40 + fused attn ------
__global__ __launch_bounds__(256) void gemm2_attn(const f16* __restrict__ A,
                                                  const f16* __restrict__ BT,
                                                  const float* __restrict__ a_src2,
                                                  const float* __restrict__ a_dst2,
                                                  float* __restrict__ hx40,
                                                  float* __restrict__ als2,
                                                  float* __restrict__ ald2) {
    __shared__ f16 Bs[48 * HC];
    int t = threadIdx.x;
    int lane = t & 63, w = t >> 6;
    int fm = lane & 15, g = lane >> 4;
    int bm = blockIdx.x * 64 + w * 16;
    int row = bm + fm;
    bool rok = row < NN;

    for (int c = t; c < 48 * 64; c += 256) {
        int brow = c >> 6, j = c & 63;
        uint4 v = make_uint4(0u, 0u, 0u, 0u);
        if (brow < NCLS) v = *(const uint4*)(BT + (size_t)brow * HC + j * 8);
        *(uint4*)&Bs[brow * HC + ((j ^ (brow & 7)) * 8)] = v;
    }

    f16x8 af[16];
#pragma unroll
    for (int kk = 0; kk < 16; ++kk) {
        uint4 r = rok ? *(const uint4*)(A + (size_t)row * HC + kk * 32 + g * 8)
                      : make_uint4(0u, 0u, 0u, 0u);
        af[kk] = __builtin_bit_cast(f16x8, r);
    }
    __syncthreads();

    f32x4 acc[3] = {};
#pragma unroll
    for (int kk = 0; kk < 16; ++kk) {
#pragma unroll
        for (int nt = 0; nt < 3; ++nt) {
            f16x8 b = *(const f16x8*)
                &Bs[(nt * 16 + fm) * HC + (((kk * 4 + g) ^ (fm & 7)) * 8)];
            acc[nt] = MFMA16(af[kk], b, acc[nt]);
        }
    }

    float a2s[3], a2d[3];
#pragma unroll
    for (int nt = 0; nt < 3; ++nt) {
        int col = nt * 16 + fm;
        a2s[nt] = (col < NCLS) ? a_src2[col] : 0.f;
        a2d[nt] = (col < NCLS) ? a_dst2[col] : 0.f;
    }
#pragma unroll
    for (int r = 0; r < 4; ++r) {
        int orow = bm + g * 4 + r;
        float s = acc[0][r] * a2s[0] + acc[1][r] * a2s[1] + acc[2][r] * a2s[2];
        float d = acc[0][r] * a2d[0] + acc[1][r] * a2d[1] + acc[2][r] * a2d[2];
#pragma unroll
        for (int off = 1; off < 16; off <<= 1) {
            s += __shfl_xor(s, off);
            d += __shfl_xor(d, off);
        }
        if (orow < NN) {
            if (fm == 0) { nt_f(&als2[orow], s); nt_f(&ald2[orow], d); }
#pragma unroll
            for (int nt = 0; nt < 3; ++nt) {
                int col = nt * 16 + fm;
                if (col < NCLS)
                    nt_f(&hx40[(size_t)orow * NCLS + col], acc[nt][r]);
            }
        }
    }
}

// ---------- aggregate: 2 waves/node, quad split, v_fma_mix accumulate ----------
__global__ __launch_bounds__(256) void agg_ell(const f16* __restrict__ hx2,
                                               const float* __restrict__ al_s,
                                               const float* __restrict__ al_d,
                                               const int* __restrict__ cnt,
                                               const int* __restrict__ ell,
                                               const float* __restrict__ bias,
                                               f16* __restrict__ outF) {
    __shared__ float accbuf[2][64][8];
    __shared__ float denbuf[2][64];
    int t = threadIdx.x;
    int lane = t & 63, w = t >> 6;
    int p = w >> 1, sub = w & 1;
    int n = blockIdx.x * 2 + p;
    bool nok = n < NN;
    int ch = lane * 8;
    int h = lane >> 3;
    float acc[8] = {0.f, 0.f, 0.f, 0.f, 0.f, 0.f, 0.f, 0.f};
    float den = 0.f;
    if (nok) {
        float ald = al_d[n * HH + h];
        int dg = cnt[n]; if (dg > ELLW) dg = ELLW;
        const int* ep = ell + (size_t)n * ELLW;
        int nq = dg >> 2;
        for (int q = sub; q < nq; q += 2) {
            int4 ss = *(const int4*)(ep + (q << 2));
            float e0 = al_s[ss.x * HH + h], e1 = al_s[ss.y * HH + h];
            float e2 = al_s[ss.z * HH + h], e3 = al_s[ss.w * HH + h];
            uint4 v0 = *(const uint4*)(hx2 + (size_t)ss.x * HC + ch);
            uint4 v1 = *(const uint4*)(hx2 + (size_t)ss.y * HC + ch);
            uint4 v2 = *(const uint4*)(hx2 + (size_t)ss.z * HC + ch);
            uint4 v3 = *(const uint4*)(hx2 + (size_t)ss.w * HC + ch);
            e0 += ald; e0 = e0 > 0.f ? e0 : 0.2f * e0;
            e1 += ald; e1 = e1 > 0.f ? e1 : 0.2f * e1;
            e2 += ald; e2 = e2 > 0.f ? e2 : 0.2f * e2;
            e3 += ald; e3 = e3 > 0.f ? e3 : 0.2f * e3;
            float w0 = __expf(e0), w1 = __expf(e1);
            float w2 = __expf(e2), w3 = __expf(e3);
            unsigned q0[4] = {v0.x, v0.y, v0.z, v0.w};
            unsigned q1[4] = {v1.x, v1.y, v1.z, v1.w};
            unsigned q2[4] = {v2.x, v2.y, v2.z, v2.w};
            unsigned q3[4] = {v3.x, v3.y, v3.z, v3.w};
#pragma unroll
            for (int j = 0; j < 4; ++j) {
                fmamix2(acc[2 * j], acc[2 * j + 1], q0[j], w0);
                fmamix2(acc[2 * j], acc[2 * j + 1], q1[j], w1);
                fmamix2(acc[2 * j], acc[2 * j + 1], q2[j], w2);
                fmamix2(acc[2 * j], acc[2 * j + 1], q3[j], w3);
            }
            den += w0 + w1 + w2 + w3;
        }
        if (sub == (nq & 1)) {                  // tail to lighter wave
            for (int i2 = nq << 2; i2 < dg; ++i2) {
                int s = ep[i2];
                float e = al_s[s * HH + h] + ald;
                e = e > 0.f ? e : 0.2f * e;
                float wgt = __expf(e);
                uint4 v = *(const uint4*)(hx2 + (size_t)s * HC + ch);
                unsigned qq[4] = {v.x, v.y, v.z, v.w};
#pragma unroll
                for (int j = 0; j < 4; ++j)
                    fmamix2(acc[2 * j], acc[2 * j + 1], qq[j], wgt);
                den += wgt;
            }
        }
    }
    if (sub == 1) {
#pragma unroll
        for (int j = 0; j < 8; ++j) accbuf[p][lane][j] = acc[j];
        denbuf[p][lane] = den;
    }
    __syncthreads();
    if (sub == 0 && nok) {
#pragma unroll
        for (int j = 0; j < 8; ++j) acc[j] += accbuf[p][lane][j];
        den += denbuf[p][lane];
        float inv = 1.f / (den + 1e-16f);
        float4 b0v = *(const float4*)(bias + ch);
        float4 b1v = *(const float4*)(bias + ch + 4);
        float bb[8] = {b0v.x, b0v.y, b0v.z, b0v.w, b1v.x, b1v.y, b1v.z, b1v.w};
        f16x8 o;
#pragma unroll
        for (int j = 0; j < 8; ++j) {
            float v = acc[j] * inv + bb[j];
            v = v > 0.f ? v : expm1f(v);        // ELU
            o[j] = (f16)v;
        }
        nt_u4(outF + (size_t)n * HC + ch, __builtin_bit_cast(uint4, o));
    }
}

// ---------- final aggregate (H=1, C=40), 4 waves/block ----------
__global__ __launch_bounds__(256) void agg2_final(const float* __restrict__ hx40,
                                                  const float* __restrict__ als,
                                                  const float* __restrict__ aldp,
                                                  const int* __restrict__ cnt,
                                                  const int* __restrict__ ell,
                                                  const float* __restrict__ b2,
                                                  float* __restrict__ out) {
    int t = threadIdx.x;
    int n = blockIdx.x * 4 + (t >> 6);
    int c = t & 63;
    if (n >= NN) return;
    float ald = aldp[n];
    int dg = cnt[n]; if (dg > ELLW) dg = ELLW;
    const int* ep = ell + (size_t)n * ELLW;
    float acc = 0.f, den = 0.f;
    int i = 0;
    for (; i + 4 <= dg; i += 4) {
        int4 ss = *(const int4*)(ep + i);
        float e0 = als[ss.x], e1 = als[ss.y], e2 = als[ss.z], e3 = als[ss.w];
        float v0 = 0.f, v1 = 0.f, v2 = 0.f, v3 = 0.f;
        if (c < NCLS) {
            v0 = hx40[(size_t)ss.x * NCLS + c];
            v1 = hx40[(size_t)ss.y * NCLS + c];
            v2 = hx40[(size_t)ss.z * NCLS + c];
            v3 = hx40[(size_t)ss.w * NCLS + c];
        }
        e0 += ald; e0 = e0 > 0.f ? e0 : 0.2f * e0;
        e1 += ald; e1 = e1 > 0.f ? e1 : 0.2f * e1;
        e2 += ald; e2 = e2 > 0.f ? e2 : 0.2f * e2;
        e3 += ald; e3 = e3 > 0.f ? e3 : 0.2f * e3;
        float w0 = __expf(e0), w1 = __expf(e1), w2 = __expf(e2), w3 = __expf(e3);
        acc += w0 * v0 + w1 * v1 + w2 * v2 + w3 * v3;
        den += w0 + w1 + w2 + w3;
    }
    for (; i < dg; ++i) {
        int s = ep[i];
        float e = als[s] + ald;
        e = e > 0.f ? e : 0.2f * e;
        float wgt = __expf(e);
        if (c < NCLS) acc += wgt * hx40[(size_t)s * NCLS + c];
        den += wgt;
    }
    if (c < NCLS) out[(size_t)n * NCLS + c] = acc / (den + 1e-16f) + b2[c];
}

extern "C" void kernel_launch(void* const* d_in, const int* in_sizes, int n_in,
                              void* d_out, int out_size, void* d_ws, size_t ws_size,
                              hipStream_t stream) {
    const float* x   = (const float*)d_in[0];
    const int*   ei  = (const int*)  d_in[1];
    const float* W0  = (const float*)d_in[2];
    const float* as0 = (const float*)d_in[3];
    const float* ad0 = (const float*)d_in[4];
    const float* b0  = (const float*)d_in[5];
    const float* W1  = (const float*)d_in[6];
    const float* as1 = (const float*)d_in[7];
    const float* ad1 = (const float*)d_in[8];
    const float* b1  = (const float*)d_in[9];
    const float* W2  = (const float*)d_in[10];
    const float* as2 = (const float*)d_in[11];
    const float* ad2 = (const float*)d_in[12];
    const float* b2  = (const float*)d_in[13];
    float* out = (float*)d_out;

    char* p = (char*)d_ws;
    int* cnt  = (int*)p; p += 40064;
    int* ell  = (int*)p; p += (size_t)NN * ELLW * 4;    // 3.84 MB
    f16* w0T  = (f16*)p; p += HC * FIN * 2;
    f16* w1T  = (f16*)p; p += HC * HC * 2;
    f16* w2T  = (f16*)p; p += NCLS * HC * 2;
    f16* hxA  = (f16*)p; p += (size_t)NN * HC * 2;
    f16* hxB  = (f16*)p; p += (size_t)NN * HC * 2;
    f16* fA   = (f16*)p; p += (size_t)NN * HC * 2;
    f16* fB   = (f16*)p; p += (size_t)NN * HC * 2;
    float* hx40 = (float*)p; p += (size_t)NN * NCLS * 4;
    float* als0 = (float*)p; p += NN * HH * 4;
    float* ald0 = (float*)p; p += NN * HH * 4;
    float* als1 = (float*)p; p += NN * HH * 4;
    float* ald1 = (float*)p; p += NN * HH * 4;
    float* als2 = (float*)p; p += NN * 4;
    float* ald2 = (float*)p; p += NN * 4;

    const int NBR = (NN + 127) / 128;   // 79 row-chunks (layer 1)
    const int NAG = (NN + 1) / 2;       // 5000 blocks (agg)
    const int NB2 = (NN + 63) / 64;     // 157 row-blocks (layer 2)

    // 1) tiny prep: cnt zero + W0 transpose
    prep0<<<(HC * FIN + 255) / 256, 256, 0, stream>>>(W0, w0T, cnt);
    // 2) mega0: gemm L0 (316) + scatter (333) + W1 (512) + W2 (40) = 1201 blocks
    mega0<<<1201, 512, 0, stream>>>(x, w0T, as0, ad0, ei, W1, W2,
                                    hxA, als0, ald0, cnt, ell, w1T, w2T);
    // 3) agg layer 0
    agg_ell<<<NAG, 256, 0, stream>>>(hxA, als0, ald0, cnt, ell, b0, fA);
    // 4) gemm layer 1
    dim3 gA(4, NBR);
    gemm_attn<HC><<<gA, 512, 0, stream>>>(fA, w1T, as1, ad1, hxB, als1, ald1);
    // 5) agg layer 1
    agg_ell<<<NAG, 256, 0, stream>>>(hxB, als1, ald1, cnt, ell, b1, fB);
    // 6) gemm layer 2
    gemm2_attn<<<NB2, 256, 0, stream>>>(fB, w2T, as2, ad2, hx40, als2, ald2);
    // 7) final aggregate
    agg2_final<<<(NN + 3) / 4, 256, 0, stream>>>(hx40, als2, ald2, cnt, ell, b2, out);
}

// Round 8
// 199.073 us; speedup vs baseline: 2.3376x; 1.0634x over previous
//
#include <hip/hip_runtime.h>
#include <math.h>

#define NN 10000
#define EE 160000
#define ET 170000
#define FIN 256
#define HH 8
#define HC 512
#define NCLS 40
#define ELLW 96

typedef _Float16 f16;
using f16x8 = __attribute__((ext_vector_type(8))) _Float16;
using f32x4 = __attribute__((ext_vector_type(4))) float;

#define MFMA16(a, b, c) __builtin_amdgcn_mfma_f32_16x16x32_f16((a), (b), (c), 0, 0, 0)

// f32 acc += f16(lo/hi of packed) * f32 w  -- forced mixed-precision FMA
__device__ __forceinline__ void fmamix2(float& alo, float& ahi, unsigned pk, float w) {
    asm("v_fma_mix_f32 %0, %1, %2, %0 op_sel:[0,0,0] op_sel_hi:[1,0,0]"
        : "+v"(alo) : "v"(pk), "v"(w));
    asm("v_fma_mix_f32 %0, %1, %2, %0 op_sel:[1,0,0] op_sel_hi:[1,0,0]"
        : "+v"(ahi) : "v"(pk), "v"(w));
}

// ---------- prep0: cnt zero + W0 transpose (tiny) ----------
__global__ __launch_bounds__(256) void prep0(const float* __restrict__ W0,
                                             f16* __restrict__ w0T,
                                             int* __restrict__ cnt) {
    int i = blockIdx.x * 256 + threadIdx.x;
    if (i < NN) cnt[i] = 0;
    if (i < HC * FIN) {
        int n = i >> 8, k = i & 255;
        w0T[i] = (f16)W0[(size_t)k * HC + n];
    }
}

// ---------- mega0: gemmL0 (fp32 A) + scatter + W1/W2 transpose ----------
__global__ __launch_bounds__(512) void mega0(const float* __restrict__ x,
                                             const f16* __restrict__ w0T,
                                             const float* __restrict__ a_src,
                                             const float* __restrict__ a_dst,
                                             const int* __restrict__ ei,
                                             const float* __restrict__ W1,
                                             const float* __restrict__ W2,
                                             f16* __restrict__ hx2,
                                             float* __restrict__ al_s,
                                             float* __restrict__ al_d,
                                             int* __restrict__ cnt,
                                             int* __restrict__ ell,
                                             f16* __restrict__ w1T,
                                             f16* __restrict__ w2T) {
    __shared__ f16 Bs[64 * FIN];          // 32 KB (reused as 128x64 out-tile)
    int b = blockIdx.x;
    int t = threadIdx.x;
    if (b >= 316) {
        if (b < 649) {                    // scatter
            int e = (b - 316) * 512 + t;
            if (e < ET) {
                int s, d;
                if (e < EE) { s = ei[e]; d = ei[EE + e]; }
                else        { s = e - EE; d = s; }
                int pos = atomicAdd(&cnt[d], 1);
                if (pos < ELLW) ell[(size_t)d * ELLW + pos] = s;
            }
        } else if (b < 1161) {            // W1 transpose
            int j = (b - 649) * 512 + t;
            int n = j >> 9, k = j & 511;
            w1T[j] = (f16)W1[(size_t)k * HC + n];
        } else {                          // W2 transpose
            int j = (b - 1161) * 512 + t;
            if (j < NCLS * HC) {
                int n = j >> 9, k = j & 511;
                w2T[j] = (f16)W2[(size_t)k * NCLS + n];
            }
        }
        return;
    }
    // ---- gemm L0: fp32 A rows -> f16 frags, B-resident LDS ----
    int hp = b & 3, chunk = b >> 2;
    int lane = t & 63, w = t >> 6;
    int fm = lane & 15, g = lane >> 4;
    int bmbase = chunk * 128;
    int bm = bmbase + w * 16;
    int row = bm + fm;
    bool rok = row < NN;

    f16x8 af[8];
#pragma unroll
    for (int kk = 0; kk < 8; ++kk) {
        float4 lo = make_float4(0.f, 0.f, 0.f, 0.f), hi = lo;
        if (rok) {
            const float* ap = x + (size_t)row * FIN + kk * 32 + g * 8;
            lo = *(const float4*)ap;
            hi = *(const float4*)(ap + 4);
        }
        f16x8 v;
        v[0] = (f16)lo.x; v[1] = (f16)lo.y; v[2] = (f16)lo.z; v[3] = (f16)lo.w;
        v[4] = (f16)hi.x; v[5] = (f16)hi.y; v[6] = (f16)hi.z; v[7] = (f16)hi.w;
        af[kk] = v;
    }

    for (int sl = 0; sl < 2; ++sl) {
        int h = hp * 2 + sl;
        const f16* bsrc = w0T + (size_t)h * 64 * FIN;
        for (int c = t; c < 64 * 32; c += 512) {
            int brow = c >> 5, j = c & 31;
            uint4 v = *(const uint4*)(bsrc + (size_t)brow * FIN + j * 8);
            *(uint4*)&Bs[(size_t)brow * FIN + ((j ^ (brow & 7)) * 8)] = v;
        }
        __syncthreads();

        f32x4 acc[4] = {};
#pragma unroll
        for (int kk = 0; kk < 8; ++kk) {
#pragma unroll
            for (int nt = 0; nt < 4; ++nt) {
                f16x8 bb = *(const f16x8*)
                    &Bs[(nt * 16 + fm) * FIN + (((kk * 4 + g) ^ (fm & 7)) * 8)];
                acc[nt] = MFMA16(af[kk], bb, acc[nt]);
            }
        }

        // ---- attn epilogue: al_s / al_d ----
        float asc[4], adc[4];
#pragma unroll
        for (int nt = 0; nt < 4; ++nt) {
            asc[nt] = a_src[h * 64 + nt * 16 + fm];
            adc[nt] = a_dst[h * 64 + nt * 16 + fm];
        }
#pragma unroll
        for (int r = 0; r < 4; ++r) {
            int orow = bm + g * 4 + r;          // C/D: row=(lane>>4)*4+reg
            float s = acc[0][r] * asc[0] + acc[1][r] * asc[1] +
                      acc[2][r] * asc[2] + acc[3][r] * asc[3];
            float d = acc[0][r] * adc[0] + acc[1][r] * adc[1] +
                      acc[2][r] * adc[2] + acc[3][r] * adc[3];
#pragma unroll
            for (int off = 1; off < 16; off <<= 1) {
                s += __shfl_xor(s, off);
                d += __shfl_xor(d, off);
            }
            if (orow < NN && fm == 0) {
                al_s[orow * 8 + h] = s;
                al_d[orow * 8 + h] = d;
            }
        }

        // ---- coalesced hx2 store: LDS transpose (reuse Bs) ----
        __syncthreads();                        // all MFMA reads of Bs done
        {
            int swz = g << 3;                   // ((trow>>2)&3)<<3 == g<<3
#pragma unroll
            for (int r = 0; r < 4; ++r) {
                int trow = w * 16 + g * 4 + r;
#pragma unroll
                for (int nt = 0; nt < 4; ++nt)
                    Bs[trow * 64 + ((nt * 16 + fm) ^ swz)] = (f16)acc[nt][r];
            }
        }
        __syncthreads();
        for (int q = t; q < 1024; q += 512) {   // 128 rows x 8 uint4
            int trow = q >> 3, j = q & 7;
            int orow2 = bmbase + trow;
            if (orow2 < NN) {
                int sw2 = ((trow >> 2) & 3) << 3;
                uint4 v = *(const uint4*)&Bs[trow * 64 + ((j * 8) ^ sw2)];
                *(uint4*)&hx2[(size_t)orow2 * HC + h * 64 + j * 8] = v;
            }
        }
        __syncthreads();                        // before next sl staging
    }
}

// ---------- GEMM + fused attn (f16 A), layer 1 ----------
template <int K>
__global__ __launch_bounds__(512) void gemm_attn(const f16* __restrict__ A,
                                                 const f16* __restrict__ BT,
                                                 const float* __restrict__ a_src,
                                                 const float* __restrict__ a_dst,
                                                 f16* __restrict__ hx2,
                                                 float* __restrict__ al_s,
                                                 float* __restrict__ al_d) {
    constexpr int KK = K / 32;
    constexpr int CH = K / 8;
    __shared__ f16 Bs[64 * K];
    int t = threadIdx.x;
    int hp = blockIdx.x;
    int lane = t & 63, w = t >> 6;
    int fm = lane & 15, g = lane >> 4;
    int bmbase = blockIdx.y * 128;
    int bm = bmbase + w * 16;
    int row = bm + fm;
    bool rok = row < NN;

    f16x8 af[KK];
#pragma unroll
    for (int kk = 0; kk < KK; ++kk) {
        uint4 r = rok ? *(const uint4*)(A + (size_t)row * K + kk * 32 + g * 8)
                      : make_uint4(0u, 0u, 0u, 0u);
        af[kk] = __builtin_bit_cast(f16x8, r);
    }

    for (int sl = 0; sl < 2; ++sl) {
        int h = hp * 2 + sl;
        const f16* bsrc = BT + (size_t)h * 64 * K;
        for (int c = t; c < 64 * CH; c += 512) {
            int brow = c / CH;
            int j = c - brow * CH;
            uint4 v = *(const uint4*)(bsrc + (size_t)brow * K + j * 8);
            *(uint4*)&Bs[(size_t)brow * K + ((j ^ (brow & 7)) * 8)] = v;
        }
        __syncthreads();

        f32x4 acc[4] = {};
#pragma unroll
        for (int kk = 0; kk < KK; ++kk) {
#pragma unroll
            for (int nt = 0; nt < 4; ++nt) {
                f16x8 b = *(const f16x8*)
                    &Bs[(nt * 16 + fm) * K + (((kk * 4 + g) ^ (fm & 7)) * 8)];
                acc[nt] = MFMA16(af[kk], b, acc[nt]);
            }
        }

        float asc[4], adc[4];
#pragma unroll
        for (int nt = 0; nt < 4; ++nt) {
            asc[nt] = a_src[h * 64 + nt * 16 + fm];
            adc[nt] = a_dst[h * 64 + nt * 16 + fm];
        }
#pragma unroll
        for (int r = 0; r < 4; ++r) {
            int orow = bm + g * 4 + r;
            float s = acc[0][r] * asc[0] + acc[1][r] * asc[1] +
                      acc[2][r] * asc[2] + acc[3][r] * asc[3];
            float d = acc[0][r] * adc[0] + acc[1][r] * adc[1] +
                      acc[2][r] * adc[2] + acc[3][r] * adc[3];
#pragma unroll
            for (int off = 1; off < 16; off <<= 1) {
                s += __shfl_xor(s, off);
                d += __shfl_xor(d, off);
            }
            if (orow < NN && fm == 0) {
                al_s[orow * 8 + h] = s;
                al_d[orow * 8 + h] = d;
            }
        }

        // ---- coalesced hx2 store: LDS transpose (reuse Bs) ----
        __syncthreads();                        // all MFMA reads of Bs done
        {
            int swz = g << 3;
#pragma unroll
            for (int r = 0; r < 4; ++r) {
                int trow = w * 16 + g * 4 + r;
#pragma unroll
                for (int nt = 0; nt < 4; ++nt)
                    Bs[trow * 64 + ((nt * 16 + fm) ^ swz)] = (f16)acc[nt][r];
            }
        }
        __syncthreads();
        for (int q = t; q < 1024; q += 512) {
            int trow = q >> 3, j = q & 7;
            int orow2 = bmbase + trow;
            if (orow2 < NN) {
                int sw2 = ((trow >> 2) & 3) << 3;
                uint4 v = *(const uint4*)&Bs[trow * 64 + ((j * 8) ^ sw2)];
                *(uint4*)&hx2[(size_t)orow2 * HC + h * 64 + j * 8] = v;
            }
        }
        __syncthreads();
    }
}

// ---------- layer 2: barrier-free B-resident GEMM 512->40 + fused attn ------
__global__ __launch_bounds__(256) void gemm2_attn(const f16* __restrict__ A,
                                                  const f16* __restrict__ BT,
                                                  const float* __restrict__ a_src2,
                                                  const float* __restrict__ a_dst2,
                                                  float* __restrict__ hx40,
                                                  float* __restrict__ als2,
                                                  float* __restrict__ ald2) {
    __shared__ f16 Bs[48 * HC];
    int t = threadIdx.x;
    int lane = t & 63, w = t >> 6;
    int fm = lane & 15, g = lane >> 4;
    int bm = blockIdx.x * 64 + w * 16;
    int row = bm + fm;
    bool rok = row < NN;

    for (int c = t; c < 48 * 64; c += 256) {
        int brow = c >> 6, j = c & 63;
        uint4 v = make_uint4(0u, 0u, 0u, 0u);
        if (brow < NCLS) v = *(const uint4*)(BT + (size_t)brow * HC + j * 8);
        *(uint4*)&Bs[brow * HC + ((j ^ (brow & 7)) * 8)] = v;
    }

    f16x8 af[16];
#pragma unroll
    for (int kk = 0; kk < 16; ++kk) {
        uint4 r = rok ? *(const uint4*)(A + (size_t)row * HC + kk * 32 + g * 8)
                      : make_uint4(0u, 0u, 0u, 0u);
        af[kk] = __builtin_bit_cast(f16x8, r);
    }
    __syncthreads();

    f32x4 acc[3] = {};
#pragma unroll
    for (int kk = 0; kk < 16; ++kk) {
#pragma unroll
        for (int nt = 0; nt < 3; ++nt) {
            f16x8 b = *(const f16x8*)
                &Bs[(nt * 16 + fm) * HC + (((kk * 4 + g) ^ (fm & 7)) * 8)];
            acc[nt] = MFMA16(af[kk], b, acc[nt]);
        }
    }

    float a2s[3], a2d[3];
#pragma unroll
    for (int nt = 0; nt < 3; ++nt) {
        int col = nt * 16 + fm;
        a2s[nt] = (col < NCLS) ? a_src2[col] : 0.f;
        a2d[nt] = (col < NCLS) ? a_dst2[col] : 0.f;
    }
#pragma unroll
    for (int r = 0; r < 4; ++r) {
        int orow = bm + g * 4 + r;
        float s = acc[0][r] * a2s[0] + acc[1][r] * a2s[1] + acc[2][r] * a2s[2];
        float d = acc[0][r] * a2d[0] + acc[1][r] * a2d[1] + acc[2][r] * a2d[2];
#pragma unroll
        for (int off = 1; off < 16; off <<= 1) {
            s += __shfl_xor(s, off);
            d += __shfl_xor(d, off);
        }
        if (orow < NN) {
            if (fm == 0) { als2[orow] = s; ald2[orow] = d; }
#pragma unroll
            for (int nt = 0; nt < 3; ++nt) {
                int col = nt * 16 + fm;
                if (col < NCLS) hx40[(size_t)orow * NCLS + col] = acc[nt][r];
            }
        }
    }
}

// ---------- aggregate: 2 waves/node, quad split, v_fma_mix accumulate ----------
__global__ __launch_bounds__(256) void agg_ell(const f16* __restrict__ hx2,
                                               const float* __restrict__ al_s,
                                               const float* __restrict__ al_d,
                                               const int* __restrict__ cnt,
                                               const int* __restrict__ ell,
                                               const float* __restrict__ bias,
                                               f16* __restrict__ outF) {
    __shared__ float accbuf[2][64][8];
    __shared__ float denbuf[2][64];
    int t = threadIdx.x;
    int lane = t & 63, w = t >> 6;
    int p = w >> 1, sub = w & 1;
    int n = blockIdx.x * 2 + p;
    bool nok = n < NN;
    int ch = lane * 8;
    int h = lane >> 3;
    float acc[8] = {0.f, 0.f, 0.f, 0.f, 0.f, 0.f, 0.f, 0.f};
    float den = 0.f;
    if (nok) {
        float ald = al_d[n * HH + h];
        int dg = cnt[n]; if (dg > ELLW) dg = ELLW;
        const int* ep = ell + (size_t)n * ELLW;
        int nq = dg >> 2;
        for (int q = sub; q < nq; q += 2) {
            int4 ss = *(const int4*)(ep + (q << 2));
            float e0 = al_s[ss.x * HH + h], e1 = al_s[ss.y * HH + h];
            float e2 = al_s[ss.z * HH + h], e3 = al_s[ss.w * HH + h];
            uint4 v0 = *(const uint4*)(hx2 + (size_t)ss.x * HC + ch);
            uint4 v1 = *(const uint4*)(hx2 + (size_t)ss.y * HC + ch);
            uint4 v2 = *(const uint4*)(hx2 + (size_t)ss.z * HC + ch);
            uint4 v3 = *(const uint4*)(hx2 + (size_t)ss.w * HC + ch);
            e0 += ald; e0 = e0 > 0.f ? e0 : 0.2f * e0;
            e1 += ald; e1 = e1 > 0.f ? e1 : 0.2f * e1;
            e2 += ald; e2 = e2 > 0.f ? e2 : 0.2f * e2;
            e3 += ald; e3 = e3 > 0.f ? e3 : 0.2f * e3;
            float w0 = __expf(e0), w1 = __expf(e1);
            float w2 = __expf(e2), w3 = __expf(e3);
            unsigned q0[4] = {v0.x, v0.y, v0.z, v0.w};
            unsigned q1[4] = {v1.x, v1.y, v1.z, v1.w};
            unsigned q2[4] = {v2.x, v2.y, v2.z, v2.w};
            unsigned q3[4] = {v3.x, v3.y, v3.z, v3.w};
#pragma unroll
            for (int j = 0; j < 4; ++j) {
                fmamix2(acc[2 * j], acc[2 * j + 1], q0[j], w0);
                fmamix2(acc[2 * j], acc[2 * j + 1], q1[j], w1);
                fmamix2(acc[2 * j], acc[2 * j + 1], q2[j], w2);
                fmamix2(acc[2 * j], acc[2 * j + 1], q3[j], w3);
            }
            den += w0 + w1 + w2 + w3;
        }
        if (sub == (nq & 1)) {                  // tail to lighter wave
            for (int i2 = nq << 2; i2 < dg; ++i2) {
                int s = ep[i2];
                float e = al_s[s * HH + h] + ald;
                e = e > 0.f ? e : 0.2f * e;
                float wgt = __expf(e);
                uint4 v = *(const uint4*)(hx2 + (size_t)s * HC + ch);
                unsigned qq[4] = {v.x, v.y, v.z, v.w};
#pragma unroll
                for (int j = 0; j < 4; ++j)
                    fmamix2(acc[2 * j], acc[2 * j + 1], qq[j], wgt);
                den += wgt;
            }
        }
    }
    if (sub == 1) {
#pragma unroll
        for (int j = 0; j < 8; ++j) accbuf[p][lane][j] = acc[j];
        denbuf[p][lane] = den;
    }
    __syncthreads();
    if (sub == 0 && nok) {
#pragma unroll
        for (int j = 0; j < 8; ++j) acc[j] += accbuf[p][lane][j];
        den += denbuf[p][lane];
        float inv = 1.f / (den + 1e-16f);
        float4 b0v = *(const float4*)(bias + ch);
        float4 b1v = *(const float4*)(bias + ch + 4);
        float bb[8] = {b0v.x, b0v.y, b0v.z, b0v.w, b1v.x, b1v.y, b1v.z, b1v.w};
        f16x8 o;
#pragma unroll
        for (int j = 0; j < 8; ++j) {
            float v = acc[j] * inv + bb[j];
            v = v > 0.f ? v : expm1f(v);        // ELU
            o[j] = (f16)v;
        }
        *(uint4*)(outF + (size_t)n * HC + ch) = __builtin_bit_cast(uint4, o);
    }
}

// ---------- final aggregate (H=1, C=40), 4 waves/block ----------
__global__ __launch_bounds__(256) void agg2_final(const float* __restrict__ hx40,
                                                  const float* __restrict__ als,
                                                  const float* __restrict__ aldp,
                                                  const int* __restrict__ cnt,
                                                  const int* __restrict__ ell,
                                                  const float* __restrict__ b2,
                                                  float* __restrict__ out) {
    int t = threadIdx.x;
    int n = blockIdx.x * 4 + (t >> 6);
    int c = t & 63;
    if (n >= NN) return;
    float ald = aldp[n];
    int dg = cnt[n]; if (dg > ELLW) dg = ELLW;
    const int* ep = ell + (size_t)n * ELLW;
    float acc = 0.f, den = 0.f;
    int i = 0;
    for (; i + 4 <= dg; i += 4) {
        int4 ss = *(const int4*)(ep + i);
        float e0 = als[ss.x], e1 = als[ss.y], e2 = als[ss.z], e3 = als[ss.w];
        float v0 = 0.f, v1 = 0.f, v2 = 0.f, v3 = 0.f;
        if (c < NCLS) {
            v0 = hx40[(size_t)ss.x * NCLS + c];
            v1 = hx40[(size_t)ss.y * NCLS + c];
            v2 = hx40[(size_t)ss.z * NCLS + c];
            v3 = hx40[(size_t)ss.w * NCLS + c];
        }
        e0 += ald; e0 = e0 > 0.f ? e0 : 0.2f * e0;
        e1 += ald; e1 = e1 > 0.f ? e1 : 0.2f * e1;
        e2 += ald; e2 = e2 > 0.f ? e2 : 0.2f * e2;
        e3 += ald; e3 = e3 > 0.f ? e3 : 0.2f * e3;
        float w0 = __expf(e0), w1 = __expf(e1), w2 = __expf(e2), w3 = __expf(e3);
        acc += w0 * v0 + w1 * v1 + w2 * v2 + w3 * v3;
        den += w0 + w1 + w2 + w3;
    }
    for (; i < dg; ++i) {
        int s = ep[i];
        float e = als[s] + ald;
        e = e > 0.f ? e : 0.2f * e;
        float wgt = __expf(e);
        if (c < NCLS) acc += wgt * hx40[(size_t)s * NCLS + c];
        den += wgt;
    }
    if (c < NCLS) out[(size_t)n * NCLS + c] = acc / (den + 1e-16f) + b2[c];
}

extern "C" void kernel_launch(void* const* d_in, const int* in_sizes, int n_in,
                              void* d_out, int out_size, void* d_ws, size_t ws_size,
                              hipStream_t stream) {
    const float* x   = (const float*)d_in[0];
    const int*   ei  = (const int*)  d_in[1];
    const float* W0  = (const float*)d_in[2];
    const float* as0 = (const float*)d_in[3];
    const float* ad0 = (const float*)d_in[4];
    const float* b0  = (const float*)d_in[5];
    const float* W1  = (const float*)d_in[6];
    const float* as1 = (const float*)d_in[7];
    const float* ad1 = (const float*)d_in[8];
    const float* b1  = (const float*)d_in[9];
    const float* W2  = (const float*)d_in[10];
    const float* as2 = (const float*)d_in[11];
    const float* ad2 = (const float*)d_in[12];
    const float* b2  = (const float*)d_in[13];
    float* out = (float*)d_out;

    char* p = (char*)d_ws;
    int* cnt  = (int*)p; p += 40064;
    int* ell  = (int*)p; p += (size_t)NN * ELLW * 4;    // 3.84 MB
    f16* w0T  = (f16*)p; p += HC * FIN * 2;
    f16* w1T  = (f16*)p; p += HC * HC * 2;
    f16* w2T  = (f16*)p; p += NCLS * HC * 2;
    f16* hxA  = (f16*)p; p += (size_t)NN * HC * 2;
    f16* hxB  = (f16*)p; p += (size_t)NN * HC * 2;
    f16* fA   = (f16*)p; p += (size_t)NN * HC * 2;
    f16* fB   = (f16*)p; p += (size_t)NN * HC * 2;
    float* hx40 = (float*)p; p += (size_t)NN * NCLS * 4;
    float* als0 = (float*)p; p += NN * HH * 4;
    float* ald0 = (float*)p; p += NN * HH * 4;
    float* als1 = (float*)p; p += NN * HH * 4;
    float* ald1 = (float*)p; p += NN * HH * 4;
    float* als2 = (float*)p; p += NN * 4;
    float* ald2 = (float*)p; p += NN * 4;

    const int NBR = (NN + 127) / 128;   // 79 row-chunks (layer 1)
    const int NAG = (NN + 1) / 2;       // 5000 blocks (agg)
    const int NB2 = (NN + 63) / 64;     // 157 row-blocks (layer 2)

    // 1) tiny prep: cnt zero + W0 transpose
    prep0<<<(HC * FIN + 255) / 256, 256, 0, stream>>>(W0, w0T, cnt);
    // 2) mega0: gemm L0 (316) + scatter (333) + W1 (512) + W2 (40) = 1201 blocks
    mega0<<<1201, 512, 0, stream>>>(x, w0T, as0, ad0, ei, W1, W2,
                                    hxA, als0, ald0, cnt, ell, w1T, w2T);
    // 3) agg layer 0
    agg_ell<<<NAG, 256, 0, stream>>>(hxA, als0, ald0, cnt, ell, b0, fA);
    // 4) gemm layer 1
    dim3 gA(4, NBR);
    gemm_attn<HC><<<gA, 512, 0, stream>>>(fA, w1T, as1, ad1, hxB, als1, ald1);
    // 5) agg layer 1
    agg_ell<<<NAG, 256, 0, stream>>>(hxB, als1, ald1, cnt, ell, b1, fB);
    // 6) gemm layer 2
    gemm2_attn<<<NB2, 256, 0, stream>>>(fB, w2T, as2, ad2, hx40, als2, ald2);
    // 7) final aggregate
    agg2_final<<<(NN + 3) / 4, 256, 0, stream>>>(hx40, als2, ald2, cnt, ell, b2, out);
}